// Round 7
// baseline (472.692 us; speedup 1.0000x reference)
//
#include <hip/hip_runtime.h>
#include <hip/hip_bf16.h>

#define NTOT 8192
#define DDIM 256
#define NRB 256                  // rows per attn block (8 waves x 32)
#define JB 32                    // j per body (one MFMA K-tile)
#define JSPLIT 8
#define JCHUNK (NTOT / JSPLIT)   // 1024 j per block
#define NITER (JCHUNK / JB)      // 32 bodies
#define NWORDS (NTOT / 32)

typedef __attribute__((ext_vector_type(8))) short short8;
typedef __attribute__((ext_vector_type(4))) float floatx4;

// ------- per-row scores + exp tables: rc=(e^s1, e^.01s1, e^-s1), etab=(e^s2, e^.01s2)
__global__ __launch_bounds__(256) void gat_scores(const float* __restrict__ h,
                                                  const float* __restrict__ a,
                                                  float4* __restrict__ rc,
                                                  float2* __restrict__ etab) {
  int row  = blockIdx.x * 4 + (threadIdx.x >> 6);
  int lane = threadIdx.x & 63;
  const float* hr = h + (size_t)row * DDIM;
  float p1 = 0.f, p2 = 0.f;
#pragma unroll
  for (int k = 0; k < DDIM / 64; ++k) {
    int idx  = lane + 64 * k;
    float hv = hr[idx];
    p1 += hv * a[idx];
    p2 += hv * a[DDIM + idx];
  }
#pragma unroll
  for (int off = 32; off > 0; off >>= 1) {
    p1 += __shfl_down(p1, off, 64);
    p2 += __shfl_down(p2, off, 64);
  }
  if (lane == 0) {
    rc[row]   = make_float4(__expf(p1), __expf(0.01f * p1), __expf(-p1), 0.f);
    etab[row] = make_float2(__expf(p2), __expf(0.01f * p2));
  }
}

// ---------------- pack adj -> word-major bitmask bitsT[jw][row] -------------
__global__ __launch_bounds__(256) void gat_pack(const int* __restrict__ adj,
                                                unsigned* __restrict__ bitsT) {
  __shared__ unsigned words[64][65];
  const int t    = threadIdx.x;
  const int lane = t & 63;
  const int w    = t >> 6;
  const int r0   = blockIdx.x * 64;
  const int jb   = blockIdx.y * 2048;

#pragma unroll 2
  for (int rr = 0; rr < 16; ++rr) {
    const int rl = w * 16 + rr;
    const int* ap = adj + (size_t)(r0 + rl) * NTOT + jb + lane * 4;
#pragma unroll
    for (int R = 0; R < 8; ++R) {
      int4 v = *(const int4*)(ap + R * 256);
      unsigned nib = (v.x > 0 ? 1u : 0u) | (v.y > 0 ? 2u : 0u) |
                     (v.z > 0 ? 4u : 0u) | (v.w > 0 ? 8u : 0u);
      unsigned b8  = nib | (__shfl_xor((int)nib, 1, 64) << 4);
      unsigned b16 = b8  | (__shfl_xor((int)b8,  2, 64) << 8);
      unsigned b32 = b16 | (__shfl_xor((int)b16, 4, 64) << 16);
      if ((lane & 7) == 0) words[rl][R * 8 + (lane >> 3)] = b32;
    }
  }
  __syncthreads();

#pragma unroll 4
  for (int kk = 0; kk < 16; ++kk) {
    const int jwl = w * 16 + kk;
    bitsT[(size_t)(jb / 32 + jwl) * NTOT + r0 + lane] = words[lane][jwl];
  }
}

// ---------------- pack h -> fragment-major bf16 hTf (padded nt-stride) ------
// hTf[((n*257 + jblk)*64 + lane)*8 + i] = H[jblk*32 + (lane>>4)*8 + i][n*16 + (lane&15)]
__global__ __launch_bounds__(256) void gat_hpack(const float* __restrict__ h,
                                                 ushort* __restrict__ hTf) {
  __shared__ float tile[64][257];
  const int t    = threadIdx.x;
  const int lane = t & 63;
  const int w    = t >> 6;
  const int quad = lane >> 4;
  const int c    = lane & 15;
  const int i0   = blockIdx.x * 64;

#pragma unroll
  for (int it = 0; it < 16; ++it) {
    int r = it * 4 + w;
    float4 v = *(const float4*)(h + (size_t)(i0 + r) * DDIM + lane * 4);
    tile[r][lane * 4 + 0] = v.x; tile[r][lane * 4 + 1] = v.y;
    tile[r][lane * 4 + 2] = v.z; tile[r][lane * 4 + 3] = v.w;
  }
  __syncthreads();

#pragma unroll
  for (int k = 0; k < 4; ++k) {
    const int n = 4 * k + w;
#pragma unroll
    for (int jbl = 0; jbl < 2; ++jbl) {
      short8 vv;
#pragma unroll
      for (int i = 0; i < 8; ++i) {
        float f = tile[jbl * 32 + quad * 8 + i][n * 16 + c];
        __hip_bfloat16 b = __float2bfloat16(f);
        vv[i] = *(short*)&b;
      }
      *(short8*)(hTf + ((size_t)(n * 257 + i0 / 32 + jbl) * 64 + lane) * 8) = vv;
    }
  }
}

// ---------------- fused softmax + P@h: j-shared waves, LDS-staged B ---------
// Grid (32 rowgroups, 8 jsplit) x 512 thr. Block: rows [bx*256, +256),
// j in [by*1024, +1024). B-tile (16KB) staged ONCE per body via global_load_lds,
// consumed by all 8 waves from LDS. fp32 partials to ws; reduce kernel finishes.
__global__ __launch_bounds__(512, 2) void gat_attn(const ushort* __restrict__ hTf,
                                                   const unsigned* __restrict__ bitsT,
                                                   const float4* __restrict__ rc,
                                                   const float2* __restrict__ etab,
                                                   float* __restrict__ part,
                                                   float* __restrict__ lpart) {
  __shared__ ushort Bt[2][16][512];   // [parity][nt][lane*8+i] = 32 KB

  const int t    = threadIdx.x;
  const int lane = t & 63;
  const int w    = t >> 6;
  const int quad = lane >> 4;
  const int c    = lane & 15;
  const int bx   = blockIdx.x;
  const int by   = blockIdx.y;
  const int rbase = bx * NRB + w * 32;     // this wave's 32 rows
  const int jbase = by * JCHUNK;
  const int jb32  = jbase / 32;

  // per-row constants for the two 16-row A-fragments
  const float4 rc0 = rc[rbase + c];
  const float4 rc1 = rc[rbase + 16 + c];
  const float E10 = rc0.x, E20 = rc0.y, T0 = rc0.z;
  const float E11 = rc1.x, E21 = rc1.y, T1 = rc1.z;

  floatx4 acc[2][16];
#pragma unroll
  for (int rt = 0; rt < 2; ++rt)
#pragma unroll
    for (int nt = 0; nt < 16; ++nt) acc[rt][nt] = (floatx4){0.f, 0.f, 0.f, 0.f};
  float lp0 = 0.f, lp1 = 0.f;

  // ---- prologue: stage body 0 into Bt[0]; prefetch body-0 masks/etab ----
#pragma unroll
  for (int q = 0; q < 2; ++q) {
    const int nt = 2 * w + q;
    const ushort* gsrc = hTf + (size_t)(nt * 257 + jb32) * 512 + lane * 8;
    __builtin_amdgcn_global_load_lds(
        (const __attribute__((address_space(1))) void*)gsrc,
        (__attribute__((address_space(3))) void*)&Bt[0][nt][0], 16, 0, 0);
  }
  unsigned W0 = bitsT[(size_t)jb32 * NTOT + rbase + c];
  unsigned W1 = bitsT[(size_t)jb32 * NTOT + rbase + 16 + c];
  const float* etp = (const float*)etab + ((size_t)jbase + quad * 8) * 2;
  float4 f0 = ((const float4*)etp)[0];
  float4 f1 = ((const float4*)etp)[1];
  float4 f2 = ((const float4*)etp)[2];
  float4 f3 = ((const float4*)etp)[3];

  for (int jt = 0; jt < NITER; ++jt) {
    const int p = jt & 1;
    __syncthreads();                       // Bt[p] staged; Bt[p^1] free

    // ---- stage body jt+1 into Bt[p^1] (DMA; drains at next barrier) ----
    if (jt + 1 < NITER) {
#pragma unroll
      for (int q = 0; q < 2; ++q) {
        const int nt = 2 * w + q;
        const ushort* gsrc =
            hTf + (size_t)(nt * 257 + jb32 + jt + 1) * 512 + lane * 8;
        __builtin_amdgcn_global_load_lds(
            (const __attribute__((address_space(1))) void*)gsrc,
            (__attribute__((address_space(3))) void*)&Bt[p ^ 1][nt][0], 16, 0, 0);
      }
    }

    // ---- P-build from tables (no local arrays -> no scratch risk) ----
    const unsigned bm0 = (W0 >> (quad * 8)) & 0xffu;
    const unsigned bm1 = (W1 >> (quad * 8)) & 0xffu;
    short8 pa0, pa1;
#define PB(i, ex, ey)                                                   \
    {                                                                   \
      const float mm0 = (float)((bm0 >> (i)) & 1u);                     \
      const float mm1 = (float)((bm1 >> (i)) & 1u);                     \
      float p0v = (((ex) > T0) ? E10 * (ex) : E20 * (ey)) * mm0;        \
      float p1v = (((ex) > T1) ? E11 * (ex) : E21 * (ey)) * mm1;        \
      lp0 += p0v; lp1 += p1v;                                           \
      __hip_bfloat16 q0 = __float2bfloat16(p0v);                        \
      __hip_bfloat16 q1 = __float2bfloat16(p1v);                        \
      pa0[i] = *(short*)&q0; pa1[i] = *(short*)&q1;                     \
    }
    PB(0, f0.x, f0.y) PB(1, f0.z, f0.w)
    PB(2, f1.x, f1.y) PB(3, f1.z, f1.w)
    PB(4, f2.x, f2.y) PB(5, f2.z, f2.w)
    PB(6, f3.x, f3.y) PB(7, f3.z, f3.w)
#undef PB

    // ---- prefetch next body's mask words + etab ----
    if (jt + 1 < NITER) {
      const size_t jw = (size_t)(jb32 + jt + 1);
      W0 = bitsT[jw * NTOT + rbase + c];
      W1 = bitsT[jw * NTOT + rbase + 16 + c];
      const float* en = etp + (size_t)(jt + 1) * 64;
      f0 = ((const float4*)en)[0];
      f1 = ((const float4*)en)[1];
      f2 = ((const float4*)en)[2];
      f3 = ((const float4*)en)[3];
    }

    // ---- MFMA: B-frags via ds_read_b128 from staged tile ----
    const ushort* bb = &Bt[p][0][lane * 8];
#pragma unroll
    for (int nt = 0; nt < 16; ++nt) {
      short8 bfr = *(const short8*)(bb + nt * 512);
      acc[0][nt] = __builtin_amdgcn_mfma_f32_16x16x32_bf16(pa0, bfr, acc[0][nt], 0, 0, 0);
      acc[1][nt] = __builtin_amdgcn_mfma_f32_16x16x32_bf16(pa1, bfr, acc[1][nt], 0, 0, 0);
    }
  }

  // ---- epilogue: write fp32 partials (no atomics; (by,row) unique) ----
  lp0 += __shfl_xor(lp0, 16, 64); lp0 += __shfl_xor(lp0, 32, 64);
  lp1 += __shfl_xor(lp1, 16, 64); lp1 += __shfl_xor(lp1, 32, 64);
  if (quad == 0) {
    lpart[(size_t)by * NTOT + rbase + c]      = lp0;
    lpart[(size_t)by * NTOT + rbase + 16 + c] = lp1;
  }
  float* pp = part + ((size_t)by * NTOT + rbase) * DDIM;
#pragma unroll
  for (int rt = 0; rt < 2; ++rt)
#pragma unroll
    for (int nt = 0; nt < 16; ++nt)
#pragma unroll
      for (int reg = 0; reg < 4; ++reg)
        pp[(size_t)(rt * 16 + quad * 4 + reg) * DDIM + nt * 16 + c] =
            acc[rt][nt][reg];
}

// ---------------- reduce j-split partials + softmax divide ------------------
__global__ __launch_bounds__(256) void gat_reduce(const float* __restrict__ part,
                                                  const float* __restrict__ lpart,
                                                  float* __restrict__ out) {
  const int row = blockIdx.x;
  const int t   = threadIdx.x;
  float l = 0.f;
#pragma unroll
  for (int js = 0; js < JSPLIT; ++js) l += lpart[(size_t)js * NTOT + row];
  float s = 0.f;
#pragma unroll
  for (int js = 0; js < JSPLIT; ++js)
    s += part[((size_t)js * NTOT + row) * DDIM + t];
  out[(size_t)row * DDIM + t] = s / l;
}

extern "C" void kernel_launch(void* const* d_in, const int* in_sizes, int n_in,
                              void* d_out, int out_size, void* d_ws, size_t ws_size,
                              hipStream_t stream) {
  const float* h   = (const float*)d_in[0];
  const int*   adj = (const int*)d_in[1];
  const float* a   = (const float*)d_in[2];
  float* out = (float*)d_out;
  char* ws = (char*)d_ws;

  float4*   rc    = (float4*)(ws);                        // 128 KB @ 0
  float2*   etab  = (float2*)(ws + (128 << 10));          // 64 KB  @ 128K
  unsigned* bitsT = (unsigned*)(ws + (1 << 20));          // 8 MB   @ 1M
  ushort*   hTf   = (ushort*)(ws + (10 << 20));           // ~4.2MB @ 10M
  float*    part  = (float*)(ws + (16 << 20));            // 64 MB  @ 16M
  float*    lpart = (float*)(ws + (82 << 20));            // 256 KB @ 82M

  gat_scores<<<NTOT / 4, 256, 0, stream>>>(h, a, rc, etab);
  gat_pack<<<dim3(NTOT / 64, 4), 256, 0, stream>>>(adj, bitsT);
  gat_hpack<<<NTOT / 64, 256, 0, stream>>>(h, hTf);
  gat_attn<<<dim3(NTOT / NRB, JSPLIT), 512, 0, stream>>>(hTf, bitsT, rc, etab, part, lpart);
  gat_reduce<<<NTOT, 256, 0, stream>>>(part, lpart, out);
}